// Round 8
// baseline (359.570 us; speedup 1.0000x reference)
//
#include <hip/hip_runtime.h>

#define KC 4096
#define DD 256
#define BB 32768
#define P_BETA 0.25f
#define P_DECAY 0.99f
#define P_EPS 1e-5f
#define TAU 0.5f
#define CHUNK 32

typedef __attribute__((ext_vector_type(8))) short bf16x8;
typedef __attribute__((ext_vector_type(4))) float f32x4;

static __device__ __forceinline__ unsigned short f2bf(float f) {
    unsigned int u = __float_as_uint(f);
    unsigned int r = (u + 0x7fffu + ((u >> 16) & 1u)) >> 16;
    return (unsigned short)r;
}
static __device__ __forceinline__ float bf2f(unsigned short h) {
    return __uint_as_float(((unsigned int)h) << 16);
}
static __device__ __forceinline__ void gload_lds16(const void* g, void* s) {
    __builtin_amdgcn_global_load_lds(
        (const __attribute__((address_space(1))) unsigned int*)g,
        (__attribute__((address_space(3))) unsigned int*)s, 16, 0, 0);
}

// ---------------------------------------------------------------------------
// Fused prep: blocks [0,8192) convert z + per-block z^2 partial;
// [8192,9216) convert cb + c_norm; block 9216 zeros cnt.
// ---------------------------------------------------------------------------
#define ZBLK (BB * DD / 4 / 256)   // 8192
#define CBLK (KC * DD / 4 / 256)   // 1024
__global__ __launch_bounds__(256) void convert_all_kernel(
    const float* __restrict__ z, const float* __restrict__ cb,
    unsigned short* __restrict__ zb, unsigned short* __restrict__ cbb,
    float* __restrict__ cn, int* __restrict__ cnt,
    float* __restrict__ z2_parts) {
    const int b = blockIdx.x;
    if (b < ZBLK) {
        int t = b * 256 + threadIdx.x;
        float4 v = ((const float4*)z)[t];
        *(ushort4*)&zb[(size_t)t * 4] =
            make_ushort4(f2bf(v.x), f2bf(v.y), f2bf(v.z), f2bf(v.w));
        float s = v.x * v.x + v.y * v.y + v.z * v.z + v.w * v.w;
#pragma unroll
        for (int m = 32; m; m >>= 1) s += __shfl_xor(s, m);
        __shared__ float ls[4];
        if ((threadIdx.x & 63) == 0) ls[threadIdx.x >> 6] = s;
        __syncthreads();
        if (threadIdx.x == 0) z2_parts[b] = ls[0] + ls[1] + ls[2] + ls[3];
    } else if (b < ZBLK + CBLK) {
        int t = (b - ZBLK) * 256 + threadIdx.x;
        int lane = threadIdx.x & 63;
        int row = (b - ZBLK) * 4 + (threadIdx.x >> 6);
        float4 v = ((const float4*)cb)[t];
        *(ushort4*)&cbb[(size_t)t * 4] =
            make_ushort4(f2bf(v.x), f2bf(v.y), f2bf(v.z), f2bf(v.w));
        float s = v.x * v.x + v.y * v.y + v.z * v.z + v.w * v.w;
#pragma unroll
        for (int m = 32; m; m >>= 1) s += __shfl_xor(s, m);
        if (lane == 0) cn[row] = s;
    } else {
        int4* p = (int4*)cnt;
        int4 zv = make_int4(0, 0, 0, 0);
#pragma unroll
        for (int j = 0; j < 4; ++j) p[threadIdx.x * 4 + j] = zv;
    }
}

// ---------------------------------------------------------------------------
// MFMA argmin screening (plain bf16), persistent A-tile, XOR swizzle.
// Emits per-row top-2 per K-half.  (unchanged)
// ---------------------------------------------------------------------------
__global__ __launch_bounds__(256, 2) void
mfma_argmin_kernel(const unsigned short* __restrict__ zb,
                   const unsigned short* __restrict__ cbb,
                   const float* __restrict__ cn,
                   float4* __restrict__ cand) {
    __shared__ unsigned short As[128 * 256];
    __shared__ unsigned short Bs[128 * 64];

    const int tid = threadIdx.x;
    const int l = tid & 63, w = tid >> 6;
    const int xcd = blockIdx.x & 7;
    const int half = xcd >> 2;
    const int rb = (blockIdx.x >> 3) * 4 + (xcd & 3);
    const int row0 = rb * 128;
    const int col0 = half * 2048;
    const int wm = w & 1, wn = w >> 1;
    const int m_off = wm * 64, n_off = wn * 64;
    const int lm = l & 15, lq = l >> 4;

    {
        const int lrow = w * 2 + (l >> 5);
        const int coff = ((l & 31) ^ lrow) * 8;
#pragma unroll
        for (int i = 0; i < 16; ++i) {
            gload_lds16(zb + (size_t)(row0 + i * 8 + lrow) * DD + coff,
                        &As[(i * 8 + w * 2) * 256]);
        }
    }

    const int srow = l >> 3;
    const int scol = ((l & 7) ^ srow) * 8;
    const int g0 = w * 4;

    float best[16];
    int bidx[16];
#pragma unroll
    for (int s = 0; s < 16; ++s) { best[s] = 3.4e38f; bidx[s] = 0; }

    for (int kc = 0; kc < 2048; kc += 128) {
        f32x4 acc[4][4];
#pragma unroll
        for (int a = 0; a < 4; ++a)
#pragma unroll
            for (int b = 0; b < 4; ++b) acc[a][b] = (f32x4){0.f, 0.f, 0.f, 0.f};

        for (int dc = 0; dc < 4; ++dc) {
#pragma unroll
            for (int j = 0; j < 4; ++j) {
                const int g = g0 + j;
                const int br = col0 + kc + g * 8 + srow;
                gload_lds16(cbb + (size_t)br * DD + dc * 64 + scol, &Bs[g * 512]);
            }
            __syncthreads();
#pragma unroll
            for (int ks = 0; ks < 2; ++ks) {
                bf16x8 af[4], bfr[4];
                const int cbi = dc * 8 + ks * 4 + lq;
#pragma unroll
                for (int tm = 0; tm < 4; ++tm) {
                    int r = m_off + tm * 16 + lm;
                    af[tm] = *(const bf16x8*)&As[r * 256 + ((cbi ^ (r & 7)) * 8)];
                }
#pragma unroll
                for (int tn = 0; tn < 4; ++tn) {
                    int r = n_off + tn * 16 + lm;
                    bfr[tn] = *(const bf16x8*)&Bs[r * 64 + (((ks * 4 + lq) ^ (r & 7)) * 8)];
                }
#pragma unroll
                for (int tm = 0; tm < 4; ++tm)
#pragma unroll
                    for (int tn = 0; tn < 4; ++tn)
                        acc[tm][tn] = __builtin_amdgcn_mfma_f32_16x16x32_bf16(
                            af[tm], bfr[tn], acc[tm][tn], 0, 0, 0);
            }
            __syncthreads();
        }
#pragma unroll
        for (int tn = 0; tn < 4; ++tn) {
            const int col = col0 + kc + n_off + tn * 16 + lm;
            const float cnv = cn[col];
#pragma unroll
            for (int tm = 0; tm < 4; ++tm)
#pragma unroll
                for (int r = 0; r < 4; ++r) {
                    float dist = fmaf(-2.0f, acc[tm][tn][r], cnv);
                    int s = tm * 4 + r;
                    if (dist < best[s]) { best[s] = dist; bidx[s] = col; }
                }
        }
    }

    float v2[16];
    int i2[16];
#pragma unroll
    for (int s = 0; s < 16; ++s) { v2[s] = 3.4e38f; i2[s] = 0x7fffffff; }
#pragma unroll
    for (int m = 1; m < 16; m <<= 1) {
#pragma unroll
        for (int s = 0; s < 16; ++s) {
            float w1 = __shfl_xor(best[s], m); int j1 = __shfl_xor(bidx[s], m);
            float w2 = __shfl_xor(v2[s], m);   int j2 = __shfl_xor(i2[s], m);
            bool b = (w1 < best[s]) || (w1 == best[s] && j1 < bidx[s]);
            if (b) {
                bool c = (best[s] < w2) || (best[s] == w2 && bidx[s] < j2);
                v2[s] = c ? best[s] : w2; i2[s] = c ? bidx[s] : j2;
                best[s] = w1; bidx[s] = j1;
            } else {
                bool c = (w1 < v2[s]) || (w1 == v2[s] && j1 < i2[s]);
                v2[s] = c ? w1 : v2[s]; i2[s] = c ? j1 : i2[s];
            }
        }
    }

    float4* red = (float4*)As;
    if (lm == 0) {
#pragma unroll
        for (int tm = 0; tm < 4; ++tm)
#pragma unroll
            for (int r = 0; r < 4; ++r) {
                int s = tm * 4 + r;
                int row_local = m_off + tm * 16 + lq * 4 + r;
                red[wn * 128 + row_local] =
                    make_float4(best[s], __int_as_float(bidx[s]), v2[s], __int_as_float(i2[s]));
            }
    }
    __syncthreads();
    if (tid < 128) {
        float4 a = red[tid], b = red[128 + tid];
        float av1 = a.x, av2 = a.z; int ai1 = __float_as_int(a.y), ai2 = __float_as_int(a.w);
        float bv1 = b.x, bv2 = b.z; int bi1 = __float_as_int(b.y), bi2 = __float_as_int(b.w);
        float v1o, v2o; int i1o, i2o;
        bool bb = (bv1 < av1) || (bv1 == av1 && bi1 < ai1);
        if (bb) {
            v1o = bv1; i1o = bi1;
            bool c = (av1 < bv2) || (av1 == bv2 && ai1 < bi2);
            v2o = c ? av1 : bv2; i2o = c ? ai1 : bi2;
        } else {
            v1o = av1; i1o = ai1;
            bool c = (bv1 < av2) || (bv1 == av2 && bi1 < ai2);
            v2o = c ? bv1 : av2; i2o = c ? bi1 : ai2;
        }
        cand[(size_t)half * BB + row0 + tid] =
            make_float4(v1o, __int_as_float(i1o), v2o, __int_as_float(i2o));
    }
}

// ---------------------------------------------------------------------------
// Fused: merge halves + exact f32 re-check + hist + zero dw/scalars.
// Grid = 256 blocks; threads 0..127 handle one row each; all zero dw.
// ---------------------------------------------------------------------------
__global__ __launch_bounds__(256) void merge_refine_kernel(
    const float4* __restrict__ cand, const float* __restrict__ z,
    const float* __restrict__ cb, const float* __restrict__ cn,
    int* __restrict__ idx_i, float* __restrict__ idx_f,
    int* __restrict__ cnt, float* __restrict__ dw,
    float* __restrict__ scalars /* [commit_dot, done_cnt] */) {
    // zero dw: 256 blocks x 256 threads x 4 float4 = 1M floats
    {
        float4 zv4 = make_float4(0.f, 0.f, 0.f, 0.f);
        float4* dp = (float4*)dw;
        int base = (blockIdx.x * 256 + threadIdx.x) * 4;
#pragma unroll
        for (int j = 0; j < 4; ++j) dp[base + j] = zv4;
    }
    if (blockIdx.x == 0 && threadIdx.x < 2) scalars[threadIdx.x] = 0.f;
    if (threadIdx.x >= 128) return;
    int i = blockIdx.x * 128 + threadIdx.x;
    float4 a = cand[i], b = cand[(size_t)BB + i];
    float av1 = a.x, av2 = a.z; int ai1 = __float_as_int(a.y), ai2 = __float_as_int(a.w);
    float bv1 = b.x, bv2 = b.z; int bi1 = __float_as_int(b.y), bi2 = __float_as_int(b.w);
    float v1o, v2o; int i1o, i2o;
    bool bb = (bv1 < av1) || (bv1 == av1 && bi1 < ai1);
    if (bb) {
        v1o = bv1; i1o = bi1;
        bool c = (av1 < bv2) || (av1 == bv2 && ai1 < bi2);
        v2o = c ? av1 : bv2; i2o = c ? ai1 : bi2;
    } else {
        v1o = av1; i1o = ai1;
        bool c = (bv1 < av2) || (bv1 == av2 && bi1 < ai2);
        v2o = c ? bv1 : av2; i2o = c ? bi1 : ai2;
    }
    int kb = i1o;
    if (v2o - v1o < TAU) {
        const float4* zr = (const float4*)(z + (size_t)i * DD);
        const float4* c1 = (const float4*)(cb + (size_t)i1o * DD);
        const float4* c2 = (const float4*)(cb + (size_t)i2o * DD);
        float s1x = 0, s1y = 0, s1z = 0, s1w = 0;
        float s2x = 0, s2y = 0, s2z = 0, s2w = 0;
        for (int j = 0; j < 64; ++j) {
            float4 zv = zr[j], p = c1[j], q = c2[j];
            s1x = fmaf(zv.x, p.x, s1x); s1y = fmaf(zv.y, p.y, s1y);
            s1z = fmaf(zv.z, p.z, s1z); s1w = fmaf(zv.w, p.w, s1w);
            s2x = fmaf(zv.x, q.x, s2x); s2y = fmaf(zv.y, q.y, s2y);
            s2z = fmaf(zv.z, q.z, s2z); s2w = fmaf(zv.w, q.w, s2w);
        }
        float d1 = cn[i1o] - 2.f * ((s1x + s1y) + (s1z + s1w));
        float d2 = cn[i2o] - 2.f * ((s2x + s2y) + (s2z + s2w));
        if (d2 < d1 || (d2 == d1 && i2o < i1o)) kb = i2o;
    }
    idx_i[i] = kb;
    idx_f[i] = (float)kb;
    atomicAdd(&cnt[kb], 1);
}

// ---------------------------------------------------------------------------
// 1 block: prefix->cursor, out_cluster + n, sum(cnt*cn), sum(z2 parts)
// ---------------------------------------------------------------------------
__global__ __launch_bounds__(256) void prefix_cluster_kernel(
    const int* __restrict__ cnt, const float* __restrict__ cn,
    const float* __restrict__ ema_cs, const float* __restrict__ z2_parts,
    int* __restrict__ cursor, float* __restrict__ out_cluster,
    float* __restrict__ n_ws, float* __restrict__ cc_ws,
    float* __restrict__ z2_ws) {
    __shared__ int ls[257];
    const int t = threadIdx.x;
    int local[16];
    int s = 0;
    float ns = 0.f, ccs = 0.f;
#pragma unroll
    for (int j = 0; j < 16; ++j) {
        int c = cnt[t * 16 + j];
        local[j] = s; s += c;
        float nc = ema_cs[t * 16 + j] * P_DECAY + (float)c * (1.0f - P_DECAY);
        out_cluster[t * 16 + j] = nc;
        ns += nc;
        ccs += (float)c * cn[t * 16 + j];
    }
    float z2s = 0.f;
    for (int j = t; j < ZBLK; j += 256) z2s += z2_parts[j];
    ls[t + 1] = s;
    __syncthreads();
    if (t == 0) {
        ls[0] = 0;
        for (int j = 1; j <= 256; ++j) ls[j] += ls[j - 1];
    }
    __syncthreads();
    int off = ls[t];
#pragma unroll
    for (int j = 0; j < 16; ++j) cursor[t * 16 + j] = off + local[j];
#pragma unroll
    for (int m = 32; m; m >>= 1) {
        ns += __shfl_xor(ns, m); ccs += __shfl_xor(ccs, m); z2s += __shfl_xor(z2s, m);
    }
    __shared__ float ln[4], lc[4], lz[4];
    if ((t & 63) == 0) { ln[t >> 6] = ns; lc[t >> 6] = ccs; lz[t >> 6] = z2s; }
    __syncthreads();
    if (t == 0) {
        *n_ws = ln[0] + ln[1] + ln[2] + ln[3];
        *cc_ws = lc[0] + lc[1] + lc[2] + lc[3];
        *z2_ws = lz[0] + lz[1] + lz[2] + lz[3];
    }
}

// ---------------------------------------------------------------------------
// z_q gather + bucket id scatter.  Pure gather+store (no z read, no reduce).
// ---------------------------------------------------------------------------
__global__ __launch_bounds__(256) void zq_scatter_kernel(
    const float* __restrict__ cb, const int* __restrict__ idx_i,
    float* __restrict__ zq, int* __restrict__ cursor, int* __restrict__ row_of) {
    const int w = threadIdx.x >> 6, l = threadIdx.x & 63;
    const int i = blockIdx.x * 4 + w;
    const int k = idx_i[i];
    float4 cv = ((const float4*)cb)[(size_t)k * 64 + l];
    ((float4*)zq)[(size_t)i * 64 + l] = cv;
    if (l == 0) {
        int pos = atomicAdd(&cursor[k], 1);
        row_of[pos] = i | (k << 16);
    }
}

// ---------------------------------------------------------------------------
// balanced bucket sum over code-sorted positions, reading bf16 zb.
// ---------------------------------------------------------------------------
__global__ __launch_bounds__(256) void bucket_chunk_kernel(
    const unsigned short* __restrict__ zb, const int* __restrict__ row_of,
    float* __restrict__ dw) {
    __shared__ int pk[CHUNK];
    const int t = threadIdx.x;
    const int p0 = blockIdx.x * CHUNK;
    if (t < CHUNK) pk[t] = row_of[p0 + t];
    __syncthreads();
    float acc = 0.f;
    int kprev = pk[0] >> 16;
#pragma unroll 4
    for (int j = 0; j < CHUNK; ++j) {
        int p = pk[j];
        int r = p & 0xffff, k = p >> 16;
        if (k != kprev) {
            atomicAdd(&dw[(size_t)kprev * DD + t], acc);
            acc = 0.f;
            kprev = k;
        }
        acc += bf2f(zb[(size_t)r * DD + t]);
    }
    atomicAdd(&dw[(size_t)kprev * DD + t], acc);
}

// ---------------------------------------------------------------------------
// finalize: nw, codebook, + cb.dw dot partials; last block writes commit.
// One block per code row (4096 blocks).
// ---------------------------------------------------------------------------
__global__ __launch_bounds__(256) void finalize_kernel(
    const float* __restrict__ ema_w, const float* __restrict__ dw,
    const float* __restrict__ cb, const float* __restrict__ out_cluster,
    const float* __restrict__ n_ws, const float* __restrict__ cc_ws,
    const float* __restrict__ z2_ws, float* __restrict__ scalars,
    float* __restrict__ out_ema_w, float* __restrict__ out_codebook,
    float* __restrict__ out_commit) {
    const int k = blockIdx.x, t = threadIdx.x;
    const size_t id = (size_t)k * DD + t;
    const float n = *n_ws;
    float dwv = dw[id];
    float nw = ema_w[id] * P_DECAY + dwv * (1.0f - P_DECAY);
    out_ema_w[id] = nw;
    float cl = out_cluster[k];
    float csz = (cl + P_EPS) / (n + (float)KC * P_EPS) * n;
    out_codebook[id] = nw / csz;
    // dot partial for commit
    float p = cb[id] * dwv;
#pragma unroll
    for (int m = 32; m; m >>= 1) p += __shfl_xor(p, m);
    __shared__ float ls[4];
    if ((t & 63) == 0) ls[t >> 6] = p;
    __syncthreads();
    if (t == 0) {
        atomicAdd(&scalars[0], ls[0] + ls[1] + ls[2] + ls[3]);
        __threadfence();
        unsigned int done = (unsigned int)atomicAdd((int*)&scalars[1], 1);
        if (done == KC - 1) {
            __threadfence();
            float dot = __hip_atomic_load(&scalars[0], __ATOMIC_ACQUIRE,
                                          __HIP_MEMORY_SCOPE_AGENT);
            float total = (*z2_ws) + (*cc_ws) - 2.0f * dot;
            *out_commit = P_BETA * total / (float)((size_t)BB * DD);
        }
    }
}

// ---------------------------------------------------------------------------
extern "C" void kernel_launch(void* const* d_in, const int* in_sizes, int n_in,
                              void* d_out, int out_size, void* d_ws, size_t ws_size,
                              hipStream_t stream) {
    const float* z      = (const float*)d_in[0];
    const float* cb     = (const float*)d_in[1];
    const float* ema_cs = (const float*)d_in[2];
    const float* ema_w  = (const float*)d_in[3];

    // workspace layout (16B-aligned first)
    float4* cand = (float4*)d_ws;                               // 2*BB float4
    unsigned short* zb = (unsigned short*)(cand + 2 * (size_t)BB);  // BB*DD bf16
    unsigned short* cbb = zb + (size_t)BB * DD;                 // KC*DD bf16
    float* dw = (float*)(cbb + (size_t)KC * DD);                // KC*DD f32
    float* c_norm = dw + (size_t)KC * DD;                       // KC
    int* idx_i = (int*)(c_norm + KC);                           // BB
    int* cnt = idx_i + BB;                                      // KC
    int* cursor = cnt + KC;                                     // KC
    int* row_of = cursor + KC;                                  // BB
    float* z2_parts = (float*)(row_of + BB);                    // ZBLK
    float* scalars = z2_parts + ZBLK;                           // [commit_dot, done]
    float* n_ws = scalars + 2;                                  // 1
    float* cc_ws = n_ws + 1;                                    // 1
    float* z2_ws = cc_ws + 1;                                   // 1

    float* out        = (float*)d_out;
    float* o_zq       = out;
    float* o_idx      = o_zq + (size_t)BB * DD;
    float* o_commit   = o_idx + BB;
    float* o_codebook = o_commit + 1;
    float* o_cluster  = o_codebook + (size_t)KC * DD;
    float* o_emaw     = o_cluster + KC;

    convert_all_kernel<<<ZBLK + CBLK + 1, 256, 0, stream>>>(z, cb, zb, cbb, c_norm,
                                                            cnt, z2_parts);
    mfma_argmin_kernel<<<(BB / 128) * 2, 256, 0, stream>>>(zb, cbb, c_norm, cand);
    merge_refine_kernel<<<BB / 128, 256, 0, stream>>>(cand, z, cb, c_norm, idx_i,
                                                      o_idx, cnt, dw, scalars);
    prefix_cluster_kernel<<<1, 256, 0, stream>>>(cnt, c_norm, ema_cs, z2_parts,
                                                 cursor, o_cluster, n_ws, cc_ws, z2_ws);
    zq_scatter_kernel<<<BB / 4, 256, 0, stream>>>(cb, idx_i, o_zq, cursor, row_of);
    bucket_chunk_kernel<<<BB / CHUNK, 256, 0, stream>>>(zb, row_of, dw);
    finalize_kernel<<<KC, 256, 0, stream>>>(ema_w, dw, cb, o_cluster, n_ws, cc_ws,
                                            z2_ws, scalars, o_emaw, o_codebook,
                                            o_commit);
    (void)in_sizes; (void)n_in; (void)out_size; (void)ws_size;
}